// Round 1
// baseline (584.777 us; speedup 1.0000x reference)
//
#include <hip/hip_runtime.h>
#include <cstdint>
#include <cstddef>

// ---------------- problem constants (fixed by setup_inputs) ----------------
#define Cc   512        // channels
#define Tt   16         // temporal length
#define HWn  1024       // h*w = 32*32
#define NBat 2          // batch
#define Mtot (NBat*Tt*HWn)   // 32768 sequence rows
#define Hh   8          // heads
#define CHd  64         // head dim
#define NQKV 1536       // 3*C

typedef _Float16 half8 __attribute__((ext_vector_type(8)));
typedef float    f32x4 __attribute__((ext_vector_type(4)));

// async global->LDS, 16B per lane; LDS dest = wave-uniform base + lane*16
__device__ __forceinline__ void gl_lds16(const void* g, void* l) {
  __builtin_amdgcn_global_load_lds(
      (const __attribute__((address_space(1))) unsigned int*)g,
      (__attribute__((address_space(3))) unsigned int*)l, 16, 0, 0);
}

// ---------------- K0: weights fp32 -> fp16 ----------------
__global__ __launch_bounds__(256) void wconv_k(const float* __restrict__ qw,
                                               const float* __restrict__ pw,
                                               _Float16* __restrict__ wq,
                                               _Float16* __restrict__ wp) {
  int i = blockIdx.x * 256 + threadIdx.x;          // grid 3072 -> 786432 threads
  if (i < NQKV * Cc) wq[i] = (_Float16)qw[i];
  if (i < Cc * Cc)   wp[i] = (_Float16)pw[i];
}

// ---------------- K1: LayerNorm -> Ahat fp16 [M][512] ----------------
// x layout: [b][c][t][hw]; row (b,t,hw) reduces over c (stride T*HW floats).
// Thread = one row; lanes along hw => every global access coalesced.
__global__ __launch_bounds__(256) void ln_k(const float* __restrict__ x,
                                            const float* __restrict__ g,
                                            const float* __restrict__ bln,
                                            _Float16* __restrict__ Ah) {
  int blk = blockIdx.x;                       // 128 blocks
  int bi = blk >> 6, ti = (blk >> 2) & 15, hwc = blk & 3;
  int t = threadIdx.x;
  int hw = hwc * 256 + t;
  const float* xp = x + ((size_t)bi * Cc * Tt + ti) * HWn + hw;  // + ci*(Tt*HWn)
  float s = 0.f, s2 = 0.f;
  #pragma unroll 8
  for (int ci = 0; ci < Cc; ++ci) {
    float v = xp[(size_t)ci * (Tt * HWn)];
    s += v; s2 += v * v;
  }
  float mean = s * (1.f / Cc);
  float var  = s2 * (1.f / Cc) - mean * mean;
  float rs   = rsqrtf(var + 1e-5f);
  size_t m = ((size_t)(bi * Tt + ti)) * HWn + hw;
  _Float16* dst = Ah + m * Cc;
  for (int k0 = 0; k0 < Cc; k0 += 8) {
    half8 hv;
    #pragma unroll
    for (int u = 0; u < 8; ++u) {
      int ci = k0 + u;
      float v = xp[(size_t)ci * (Tt * HWn)];
      hv[u] = (_Float16)((v - mean) * rs * g[ci] + bln[ci]);
    }
    *(half8*)(dst + k0) = hv;                 // 16B store per thread
  }
}

// ---------------- K2/K4: fp16 MFMA GEMM, m97 structure ----------------
// C[m][n] = sum_k A[m][k]*W[n][k] (+bias). A:[M][512] fp16, W:[N][512] fp16.
// 128x128 tile, 4 waves (2x2 quadrants of 64x64), BK=32, dbuf LDS,
// global_load_lds 16B staging, LDS-restaged coalesced epilogue.
template<int NCOLS, bool PROJ>
__global__ __launch_bounds__(256) void gemm_k(const _Float16* __restrict__ A,
                                              const _Float16* __restrict__ W,
                                              const float* __restrict__ bias,
                                              _Float16* __restrict__ Cout,   // !PROJ: [M][NCOLS] fp16
                                              const float* __restrict__ xres,// PROJ: x for residual
                                              float* __restrict__ outF) {    // PROJ: out (x layout)
  __shared__ union {
    struct { _Float16 A[2][128 * 32]; _Float16 B[2][128 * 32]; } s;
    float Cs[64 * 129];
  } u;

  const int tid  = threadIdx.x;
  const int wave = tid >> 6, lane = tid & 63;
  const int tile_m = blockIdx.x % (Mtot / 128);
  const int tile_n = blockIdx.x / (Mtot / 128);
  const int m0 = tile_m * 128, n0 = tile_n * 128;
  const int wm = wave >> 1, wn = wave & 1;
  const int fr = lane & 15, fk = (lane >> 4) * 8;

  f32x4 acc[4][4] = {};

  auto stage = [&](int buf, int kt) {
    const int k0 = kt * 32;
    #pragma unroll
    for (int i = 0; i < 2; ++i) {
      int rowbase = i * 64 + wave * 16;
      int row = rowbase + (lane >> 2);
      const _Float16* sa = A + (size_t)(m0 + row) * Cc + k0 + (lane & 3) * 8;
      gl_lds16(sa, &u.s.A[buf][rowbase * 32]);
      const _Float16* sb = W + (size_t)(n0 + row) * Cc + k0 + (lane & 3) * 8;
      gl_lds16(sb, &u.s.B[buf][rowbase * 32]);
    }
  };

  stage(0, 0);
  __syncthreads();

  const int NK = Cc / 32;                      // 16 K-steps
  for (int kt = 0; kt < NK; ++kt) {
    int buf = kt & 1;
    if (kt + 1 < NK) stage(buf ^ 1, kt + 1);
    half8 af[4], bf[4];
    #pragma unroll
    for (int i = 0; i < 4; ++i)
      af[i] = *(const half8*)&u.s.A[buf][(wm * 64 + i * 16 + fr) * 32 + fk];
    #pragma unroll
    for (int j = 0; j < 4; ++j)
      bf[j] = *(const half8*)&u.s.B[buf][(wn * 64 + j * 16 + fr) * 32 + fk];
    #pragma unroll
    for (int i = 0; i < 4; ++i)
      #pragma unroll
      for (int j = 0; j < 4; ++j)
        acc[i][j] = __builtin_amdgcn_mfma_f32_16x16x32_f16(af[i], bf[j], acc[i][j], 0, 0, 0);
    __syncthreads();                            // drains global_load_lds too
  }

  // epilogue: two row-halves of 64, restaged through LDS (Cs[64][129])
  const int bi_o = m0 >> 14, ti_o = (m0 >> 10) & 15, hw0 = m0 & 1023;
  #pragma unroll
  for (int r = 0; r < 2; ++r) {
    if (wm == r) {
      #pragma unroll
      for (int i = 0; i < 4; ++i)
        #pragma unroll
        for (int j = 0; j < 4; ++j)
          #pragma unroll
          for (int jj = 0; jj < 4; ++jj) {
            int row = i * 16 + (lane >> 4) * 4 + jj;     // 0..63 local
            int col = wn * 64 + j * 16 + (lane & 15);    // 0..127
            u.Cs[row * 129 + col] = acc[i][j][jj];
          }
    }
    __syncthreads();
    if (!PROJ) {
      for (int it = 0; it < 32; ++it) {
        int row = it * 2 + (tid >> 7);
        int col = tid & 127;
        float v = u.Cs[row * 129 + col] + bias[n0 + col];
        Cout[(size_t)(m0 + r * 64 + row) * NCOLS + n0 + col] = (_Float16)v;
      }
    } else {
      // out[b][c][t][hw]: rows of Cs are contiguous hw -> coalesced
      for (int it = 0; it < 32; ++it) {
        int col = it * 4 + (tid >> 6);   // channel within tile
        int row = tid & 63;              // hw within half-tile
        size_t oidx = (((size_t)(bi_o * Cc + n0 + col) * Tt) + ti_o) * HWn
                      + hw0 + r * 64 + row;
        outF[oidx] = u.Cs[row * 129 + col] + bias[n0 + col] + xres[oidx];
      }
    }
    __syncthreads();
  }
}

// ---------------- K3: attention (fp32 math, fp16 I/O) ----------------
// thread = (qi, hw_local); block = (bi, h, 16 hw). All 16 qi share k/v rows
// through L1. t=16 < MAXP=64 => rel-pos index = ki-qi+64, never clipped.
__global__ __launch_bounds__(256) void attn_k(const _Float16* __restrict__ qkv,  // [M][1536]
                                              const float* __restrict__ ktab,    // [129][64]
                                              const float* __restrict__ vtab,
                                              _Float16* __restrict__ aout) {     // [M][512]
  __shared__ float kt_s[31][64], vt_s[31][64];   // rows 49..79 of tables
  int bx = blockIdx.x;                            // grid 1024
  int bi = bx >> 9, h = (bx >> 6) & 7, hwc = bx & 63;
  int t = threadIdx.x;
  int qi = t >> 4, hwl = t & 15;
  int hw = hwc * 16 + hwl;

  for (int i = t; i < 31 * 64; i += 256) {
    (&kt_s[0][0])[i] = ktab[49 * 64 + i];
    (&vt_s[0][0])[i] = vtab[49 * 64 + i];
  }
  __syncthreads();

  size_t mq = ((size_t)(bi * Tt + qi)) * HWn + hw;
  const _Float16* qrow = qkv + mq * NQKV + h * CHd;
  float q[64];
  #pragma unroll
  for (int u = 0; u < 8; ++u) {
    half8 hv = *(const half8*)(qrow + u * 8);
    #pragma unroll
    for (int c = 0; c < 8; ++c) q[u * 8 + c] = (float)hv[c];
  }

  float s[16];
  #pragma unroll
  for (int ki = 0; ki < 16; ++ki) {
    size_t mk = ((size_t)(bi * Tt + ki)) * HWn + hw;
    const _Float16* krow = qkv + mk * NQKV + Cc + h * CHd;
    int d = ki - qi + 15;                       // 0..30
    float acc = 0.f;
    #pragma unroll
    for (int u = 0; u < 8; ++u) {
      half8 hv = *(const half8*)(krow + u * 8);
      #pragma unroll
      for (int c = 0; c < 8; ++c)
        acc += q[u * 8 + c] * ((float)hv[c] + kt_s[d][u * 8 + c]);
    }
    s[ki] = acc * 0.125f;                       // scale^2 = 1/sqrt(ch) = 1/8
  }

  float mx = s[0];
  #pragma unroll
  for (int ki = 1; ki < 16; ++ki) mx = fmaxf(mx, s[ki]);
  float sum = 0.f;
  #pragma unroll
  for (int ki = 0; ki < 16; ++ki) { s[ki] = __expf(s[ki] - mx); sum += s[ki]; }
  float inv = 1.f / sum;

  float o[64];
  #pragma unroll
  for (int c = 0; c < 64; ++c) o[c] = 0.f;
  #pragma unroll
  for (int ki = 0; ki < 16; ++ki) {
    size_t mk = ((size_t)(bi * Tt + ki)) * HWn + hw;
    const _Float16* vrow = qkv + mk * NQKV + 2 * Cc + h * CHd;
    int d = ki - qi + 15;
    float pk = s[ki];
    #pragma unroll
    for (int u = 0; u < 8; ++u) {
      half8 hv = *(const half8*)(vrow + u * 8);
      #pragma unroll
      for (int c = 0; c < 8; ++c)
        o[u * 8 + c] += pk * ((float)hv[c] + vt_s[d][u * 8 + c]);
    }
  }

  _Float16* arow = aout + mq * Cc + h * CHd;
  #pragma unroll
  for (int u = 0; u < 8; ++u) {
    half8 hv;
    #pragma unroll
    for (int c = 0; c < 8; ++c) hv[c] = (_Float16)(o[u * 8 + c] * inv);
    *(half8*)(arow + u * 8) = hv;
  }
}

// ---------------- launch ----------------
extern "C" void kernel_launch(void* const* d_in, const int* in_sizes, int n_in,
                              void* d_out, int out_size, void* d_ws, size_t ws_size,
                              hipStream_t stream) {
  const float* x      = (const float*)d_in[0];
  const float* ln_g   = (const float*)d_in[1];
  const float* ln_b   = (const float*)d_in[2];
  const float* qkv_w  = (const float*)d_in[3];
  const float* qkv_b  = (const float*)d_in[4];
  const float* k_tab  = (const float*)d_in[5];
  const float* v_tab  = (const float*)d_in[6];
  const float* proj_w = (const float*)d_in[7];
  const float* proj_b = (const float*)d_in[8];
  float* out = (float*)d_out;

  _Float16* Ah   = (_Float16*)d_ws;                    // [32768][512]
  _Float16* qkvb = Ah   + (size_t)Mtot * Cc;           // [32768][1536]
  _Float16* ab   = qkvb + (size_t)Mtot * NQKV;         // [32768][512]
  _Float16* wq   = ab   + (size_t)Mtot * Cc;           // [1536][512]
  _Float16* wp   = wq   + (size_t)NQKV * Cc;           // [512][512]

  wconv_k<<<3072, 256, 0, stream>>>(qkv_w, proj_w, wq, wp);
  ln_k<<<128, 256, 0, stream>>>(x, ln_g, ln_b, Ah);
  gemm_k<NQKV, false><<<(Mtot / 128) * (NQKV / 128), 256, 0, stream>>>(
      Ah, wq, qkv_b, qkvb, nullptr, nullptr);
  attn_k<<<1024, 256, 0, stream>>>(qkvb, k_tab, v_tab, ab);
  gemm_k<Cc, true><<<(Mtot / 128) * (Cc / 128), 256, 0, stream>>>(
      ab, wp, proj_b, nullptr, x, out);
}

// Round 2
// 495.953 us; speedup vs baseline: 1.1791x; 1.1791x over previous
//
#include <hip/hip_runtime.h>
#include <cstdint>
#include <cstddef>

// ---------------- problem constants (fixed by setup_inputs) ----------------
#define Cc   512        // channels
#define Tt   16         // temporal length
#define HWn  1024       // h*w = 32*32
#define NBat 2          // batch
#define Mtot (NBat*Tt*HWn)   // 32768 sequence rows
#define Hh   8          // heads
#define CHd  64         // head dim
#define NQKV 1536       // 3*C

typedef _Float16 half8 __attribute__((ext_vector_type(8)));
typedef float    f32x4 __attribute__((ext_vector_type(4)));

// async global->LDS, 16B per lane; LDS dest = wave-uniform base + lane*16
__device__ __forceinline__ void gl_lds16(const void* g, void* l) {
  __builtin_amdgcn_global_load_lds(
      (const __attribute__((address_space(1))) unsigned int*)g,
      (__attribute__((address_space(3))) unsigned int*)l, 16, 0, 0);
}

// ---------------- K0: weights fp32 -> fp16 ----------------
__global__ __launch_bounds__(256) void wconv_k(const float* __restrict__ qw,
                                               const float* __restrict__ pw,
                                               _Float16* __restrict__ wq,
                                               _Float16* __restrict__ wp) {
  int i = blockIdx.x * 256 + threadIdx.x;          // grid 3072 -> 786432 threads
  if (i < NQKV * Cc) wq[i] = (_Float16)qw[i];
  if (i < Cc * Cc)   wp[i] = (_Float16)pw[i];
}

// ---------------- K1: LayerNorm -> Ahat fp16 [M][512] ----------------
// x layout: [b][c][t][hw]; row (b,t,hw) reduces over c (stride T*HW floats).
// Thread = one row; lanes along hw => every global access coalesced.
__global__ __launch_bounds__(256) void ln_k(const float* __restrict__ x,
                                            const float* __restrict__ g,
                                            const float* __restrict__ bln,
                                            _Float16* __restrict__ Ah) {
  int blk = blockIdx.x;                       // 128 blocks
  int bi = blk >> 6, ti = (blk >> 2) & 15, hwc = blk & 3;
  int t = threadIdx.x;
  int hw = hwc * 256 + t;
  const float* xp = x + ((size_t)bi * Cc * Tt + ti) * HWn + hw;  // + ci*(Tt*HWn)
  float s = 0.f, s2 = 0.f;
  #pragma unroll 8
  for (int ci = 0; ci < Cc; ++ci) {
    float v = xp[(size_t)ci * (Tt * HWn)];
    s += v; s2 += v * v;
  }
  float mean = s * (1.f / Cc);
  float var  = s2 * (1.f / Cc) - mean * mean;
  float rs   = rsqrtf(var + 1e-5f);
  size_t m = ((size_t)(bi * Tt + ti)) * HWn + hw;
  _Float16* dst = Ah + m * Cc;
  for (int k0 = 0; k0 < Cc; k0 += 8) {
    half8 hv;
    #pragma unroll
    for (int u = 0; u < 8; ++u) {
      int ci = k0 + u;
      float v = xp[(size_t)ci * (Tt * HWn)];
      hv[u] = (_Float16)((v - mean) * rs * g[ci] + bln[ci]);
    }
    *(half8*)(dst + k0) = hv;                 // 16B store per thread
  }
}

// ---------------- K2/K4: fp16 MFMA GEMM ----------------
// C[m][n] = sum_k A[m][k]*W[n][k] (+bias). A:[M][512] fp16, W:[N][512] fp16.
// 128x128 tile, 4 waves (2x2 quadrants of 64x64), BK=32.
// Triple-buffered LDS, ONE raw s_barrier per K-step, counted vmcnt(4)
// (never drains in-loop), chunk-XOR bank swizzle staged via pre-swizzled
// global source (involution f(row)=(row>>1)&3 on 16B chunks).
template<int NCOLS, bool PROJ>
__global__ __launch_bounds__(256) void gemm_k(const _Float16* __restrict__ A,
                                              const _Float16* __restrict__ W,
                                              const float* __restrict__ bias,
                                              _Float16* __restrict__ Cout,   // !PROJ: [M][NCOLS] fp16
                                              const float* __restrict__ xres,// PROJ: x for residual
                                              float* __restrict__ outF) {    // PROJ: out (x layout)
  __shared__ union {
    struct { _Float16 A[3][128 * 32]; _Float16 B[3][128 * 32]; } s;  // 48 KB
    float Cs[64 * 129];
  } u;

  const int tid  = threadIdx.x;
  const int wave = tid >> 6, lane = tid & 63;
  const int NTN = NCOLS / 128;
  const int tile_m = blockIdx.x / NTN;       // tile_n fastest: consecutive
  const int tile_n = blockIdx.x % NTN;       // blocks share the A row-panel
  const int m0 = tile_m * 128, n0 = tile_n * 128;
  const int wm = wave >> 1, wn = wave & 1;
  const int fr = lane & 15;
  const int fkc = lane >> 4;                  // 16B chunk index 0..3
  const int fsw = (fr >> 1) & 3;              // read-side swizzle XOR

  f32x4 acc[4][4] = {};

  // per-lane source swizzle: lane l writes LDS slot (row = base+(l>>2), chunk=l&3);
  // that slot must hold data chunk (l&3)^f(row).
  const int srow_l = lane >> 2;               // row within 16-row group
  const int schunk = lane & 3;

  auto stage = [&](int buf, int kt) {
    const int k0 = kt * 32;
    #pragma unroll
    for (int i = 0; i < 2; ++i) {
      int rowbase = i * 64 + wave * 16;
      int row = rowbase + srow_l;
      int cg = schunk ^ ((row >> 1) & 3);
      const _Float16* sa = A + (size_t)(m0 + row) * Cc + k0 + cg * 8;
      gl_lds16(sa, &u.s.A[buf][rowbase * 32]);
      const _Float16* sb = W + (size_t)(n0 + row) * Cc + k0 + cg * 8;
      gl_lds16(sb, &u.s.B[buf][rowbase * 32]);
    }
  };

  const int NK = Cc / 32;                     // 16 K-steps
  // prologue: two tiles in flight, wait for the first
  stage(0, 0);
  stage(1, 1);
  asm volatile("s_waitcnt vmcnt(4)" ::: "memory");
  __builtin_amdgcn_s_barrier();

  int bc = 0, b1 = 1, b2 = 2;                 // rotating buffer ids
  for (int kt = 0; kt < NK; ++kt) {
    if (kt + 2 < NK) stage(b2, kt + 2);       // 4 loads into (kt+2)%3
    half8 af[4], bf[4];
    #pragma unroll
    for (int i = 0; i < 4; ++i) {
      int row = wm * 64 + i * 16 + fr;
      af[i] = *(const half8*)&u.s.A[bc][row * 32 + ((fkc ^ fsw) * 8)];
    }
    #pragma unroll
    for (int j = 0; j < 4; ++j) {
      int row = wn * 64 + j * 16 + fr;
      bf[j] = *(const half8*)&u.s.B[bc][row * 32 + ((fkc ^ fsw) * 8)];
    }
    #pragma unroll
    for (int i = 0; i < 4; ++i)
      #pragma unroll
      for (int j = 0; j < 4; ++j)
        acc[i][j] = __builtin_amdgcn_mfma_f32_16x16x32_f16(af[i], bf[j], acc[i][j], 0, 0, 0);
    if (kt < NK - 1) {
      if (kt + 2 < NK) asm volatile("s_waitcnt vmcnt(4)" ::: "memory");
      else             asm volatile("s_waitcnt vmcnt(0)" ::: "memory");
      __builtin_amdgcn_s_barrier();           // next tile staged for all waves
    }
    int t0 = bc; bc = b1; b1 = b2; b2 = t0;   // rotate
  }
  __syncthreads();                            // protect Cs union overlap

  // epilogue: two row-halves of 64, restaged through LDS (Cs[64][129])
  const int bi_o = m0 >> 14, ti_o = (m0 >> 10) & 15, hw0 = m0 & 1023;
  #pragma unroll
  for (int r = 0; r < 2; ++r) {
    if (wm == r) {
      #pragma unroll
      for (int i = 0; i < 4; ++i)
        #pragma unroll
        for (int j = 0; j < 4; ++j)
          #pragma unroll
          for (int jj = 0; jj < 4; ++jj) {
            int row = i * 16 + (lane >> 4) * 4 + jj;     // 0..63 local
            int col = wn * 64 + j * 16 + (lane & 15);    // 0..127
            u.Cs[row * 129 + col] = acc[i][j][jj];
          }
    }
    __syncthreads();
    if (!PROJ) {
      for (int it = 0; it < 32; ++it) {
        int row = it * 2 + (tid >> 7);
        int col = tid & 127;
        float v = u.Cs[row * 129 + col] + bias[n0 + col];
        Cout[(size_t)(m0 + r * 64 + row) * NCOLS + n0 + col] = (_Float16)v;
      }
    } else {
      // out[b][c][t][hw]: rows of Cs are contiguous hw -> coalesced
      for (int it = 0; it < 32; ++it) {
        int col = it * 4 + (tid >> 6);   // channel within tile
        int row = tid & 63;              // hw within half-tile
        size_t oidx = (((size_t)(bi_o * Cc + n0 + col) * Tt) + ti_o) * HWn
                      + hw0 + r * 64 + row;
        outF[oidx] = u.Cs[row * 129 + col] + bias[n0 + col] + xres[oidx];
      }
    }
    __syncthreads();
  }
}

// ---------------- K3: attention (fp32 math, fp16 I/O) ----------------
// thread = (qi, hw_local); block = (bi, h, 16 hw). All 16 qi share k/v rows
// through L1. t=16 < MAXP=64 => rel-pos index = ki-qi+64, never clipped.
__global__ __launch_bounds__(256) void attn_k(const _Float16* __restrict__ qkv,  // [M][1536]
                                              const float* __restrict__ ktab,    // [129][64]
                                              const float* __restrict__ vtab,
                                              _Float16* __restrict__ aout) {     // [M][512]
  __shared__ float kt_s[31][64], vt_s[31][64];   // rows 49..79 of tables
  int bx = blockIdx.x;                            // grid 1024
  int bi = bx >> 9, h = (bx >> 6) & 7, hwc = bx & 63;
  int t = threadIdx.x;
  int qi = t >> 4, hwl = t & 15;
  int hw = hwc * 16 + hwl;

  for (int i = t; i < 31 * 64; i += 256) {
    (&kt_s[0][0])[i] = ktab[49 * 64 + i];
    (&vt_s[0][0])[i] = vtab[49 * 64 + i];
  }
  __syncthreads();

  size_t mq = ((size_t)(bi * Tt + qi)) * HWn + hw;
  const _Float16* qrow = qkv + mq * NQKV + h * CHd;
  float q[64];
  #pragma unroll
  for (int u = 0; u < 8; ++u) {
    half8 hv = *(const half8*)(qrow + u * 8);
    #pragma unroll
    for (int c = 0; c < 8; ++c) q[u * 8 + c] = (float)hv[c];
  }

  float s[16];
  #pragma unroll
  for (int ki = 0; ki < 16; ++ki) {
    size_t mk = ((size_t)(bi * Tt + ki)) * HWn + hw;
    const _Float16* krow = qkv + mk * NQKV + Cc + h * CHd;
    int d = ki - qi + 15;                       // 0..30
    float acc = 0.f;
    #pragma unroll
    for (int u = 0; u < 8; ++u) {
      half8 hv = *(const half8*)(krow + u * 8);
      #pragma unroll
      for (int c = 0; c < 8; ++c)
        acc += q[u * 8 + c] * ((float)hv[c] + kt_s[d][u * 8 + c]);
    }
    s[ki] = acc * 0.125f;                       // scale^2 = 1/sqrt(ch) = 1/8
  }

  float mx = s[0];
  #pragma unroll
  for (int ki = 1; ki < 16; ++ki) mx = fmaxf(mx, s[ki]);
  float sum = 0.f;
  #pragma unroll
  for (int ki = 0; ki < 16; ++ki) { s[ki] = __expf(s[ki] - mx); sum += s[ki]; }
  float inv = 1.f / sum;

  float o[64];
  #pragma unroll
  for (int c = 0; c < 64; ++c) o[c] = 0.f;
  #pragma unroll
  for (int ki = 0; ki < 16; ++ki) {
    size_t mk = ((size_t)(bi * Tt + ki)) * HWn + hw;
    const _Float16* vrow = qkv + mk * NQKV + 2 * Cc + h * CHd;
    int d = ki - qi + 15;
    float pk = s[ki];
    #pragma unroll
    for (int u = 0; u < 8; ++u) {
      half8 hv = *(const half8*)(vrow + u * 8);
      #pragma unroll
      for (int c = 0; c < 8; ++c)
        o[u * 8 + c] += pk * ((float)hv[c] + vt_s[d][u * 8 + c]);
    }
  }

  _Float16* arow = aout + mq * Cc + h * CHd;
  #pragma unroll
  for (int u = 0; u < 8; ++u) {
    half8 hv;
    #pragma unroll
    for (int c = 0; c < 8; ++c) hv[c] = (_Float16)(o[u * 8 + c] * inv);
    *(half8*)(arow + u * 8) = hv;
  }
}

// ---------------- launch ----------------
extern "C" void kernel_launch(void* const* d_in, const int* in_sizes, int n_in,
                              void* d_out, int out_size, void* d_ws, size_t ws_size,
                              hipStream_t stream) {
  const float* x      = (const float*)d_in[0];
  const float* ln_g   = (const float*)d_in[1];
  const float* ln_b   = (const float*)d_in[2];
  const float* qkv_w  = (const float*)d_in[3];
  const float* qkv_b  = (const float*)d_in[4];
  const float* k_tab  = (const float*)d_in[5];
  const float* v_tab  = (const float*)d_in[6];
  const float* proj_w = (const float*)d_in[7];
  const float* proj_b = (const float*)d_in[8];
  float* out = (float*)d_out;

  _Float16* Ah   = (_Float16*)d_ws;                    // [32768][512]
  _Float16* qkvb = Ah   + (size_t)Mtot * Cc;           // [32768][1536]
  _Float16* ab   = qkvb + (size_t)Mtot * NQKV;         // [32768][512]
  _Float16* wq   = ab   + (size_t)Mtot * Cc;           // [1536][512]
  _Float16* wp   = wq   + (size_t)NQKV * Cc;           // [512][512]

  wconv_k<<<3072, 256, 0, stream>>>(qkv_w, proj_w, wq, wp);
  ln_k<<<128, 256, 0, stream>>>(x, ln_g, ln_b, Ah);
  gemm_k<NQKV, false><<<(Mtot / 128) * (NQKV / 128), 256, 0, stream>>>(
      Ah, wq, qkv_b, qkvb, nullptr, nullptr);
  attn_k<<<1024, 256, 0, stream>>>(qkvb, k_tab, v_tab, ab);
  gemm_k<Cc, true><<<(Mtot / 128) * (Cc / 128), 256, 0, stream>>>(
      ab, wp, proj_b, nullptr, x, out);
}